// Round 10
// baseline (171.806 us; speedup 1.0000x reference)
//
#include <hip/hip_runtime.h>

// Problem constants: B=8, L=64, D=768, H=12, d=64
#define DMODEL 768
#define NHEADS 12
#define RTOT   512           // B*L rows
#define BIW    9216          // NHEADS*DMODEL (per-(b,i) u/w row)

// ---------------------------------------------------------------------------
// 16x32-tile fp32 GEMM, register-double-buffered K chunks of 64.
// grid = (32, 24), 256 threads
// ---------------------------------------------------------------------------
__global__ __launch_bounds__(256) void linear16(
    const float* __restrict__ src, int ars, int scm,
    const float* __restrict__ W, const float* __restrict__ bias,
    float* __restrict__ dst, int drs, float scale)
{
    __shared__ float At[16][64];   // 4 KB
    __shared__ float Bt[64][32];   // 8 KB
    const int rt = blockIdx.x, ct = blockIdx.y, t = threadIdx.x;
    const int sk = ((ct * 32) >> 6) * scm;
    const int c  = t & 31;
    const int rg = t >> 5;             // 8 groups x 2 rows

    const int ar0 = t >> 4,          ak0 = t & 15;          // 1 float4 A
    const int bk0 = t >> 3,          bc0 = (t & 7) * 4;     // 2 float4 B
    const int bk1 = (t + 256) >> 3,  bc1 = ((t + 256) & 7) * 4;

    float4 va0, vb0, vb1;
    auto LD = [&](int kb) {
        va0 = *(const float4*)&src[(size_t)(rt * 16 + ar0) * ars + sk + kb * 64 + ak0 * 4];
        vb0 = *(const float4*)&W[(size_t)(kb * 64 + bk0) * DMODEL + ct * 32 + bc0];
        vb1 = *(const float4*)&W[(size_t)(kb * 64 + bk1) * DMODEL + ct * 32 + bc1];
    };

    LD(0);
    float acc[2] = {0.f, 0.f};

    for (int kb = 0; kb < 12; ++kb) {
        if (kb) __syncthreads();
        *(float4*)&At[ar0][ak0 * 4] = va0;
        *(float4*)&Bt[bk0][bc0] = vb0;
        *(float4*)&Bt[bk1][bc1] = vb1;
        __syncthreads();
        if (kb < 11) LD(kb + 1);
        #pragma unroll
        for (int kq = 0; kq < 16; ++kq) {
            float b0 = Bt[kq * 4 + 0][c], b1 = Bt[kq * 4 + 1][c];
            float b2 = Bt[kq * 4 + 2][c], b3 = Bt[kq * 4 + 3][c];
            #pragma unroll
            for (int i = 0; i < 2; ++i) {
                float4 a = *(const float4*)&At[rg * 2 + i][kq * 4];
                acc[i] += a.x * b0 + a.y * b1 + a.z * b2 + a.w * b3;
            }
        }
    }
    const float bb = bias[ct * 32 + c];
    #pragma unroll
    for (int i = 0; i < 2; ++i)
        dst[(size_t)(rt * 16 + rg * 2 + i) * drs + ct * 32 + c] = (acc[i] + bb) * scale;
}

// ---------------------------------------------------------------------------
// u[r, h, m] = sum_d Qp[r, h*64+d] * Wk[m, h*64+d];  cvec[r,h] = sum_d bk[h*64+d]*Qp[r,h*64+d]
// grid = (16, 12, 12), 256 threads
// ---------------------------------------------------------------------------
__global__ __launch_bounds__(256) void u_kernel(
    const float* __restrict__ qp, const float* __restrict__ Wk, const float* __restrict__ bk,
    float* __restrict__ u, float* __restrict__ cvec)
{
    __shared__ float Qt[32][64];    // 8 KB
    __shared__ float Bt[64][65];    // 16.25 KB (pad -> conflict-free b32 row reads)
    const int rt = blockIdx.x, mt = blockIdx.y, h = blockIdx.z, t = threadIdx.x;

    #pragma unroll
    for (int kk = 0; kk < 2; ++kk) {
        int i4 = t + kk * 256;
        int r = i4 >> 4, dq = i4 & 15;
        *(float4*)&Qt[r][dq * 4] =
            *(const float4*)&qp[(size_t)(rt * 32 + r) * DMODEL + h * 64 + dq * 4];
    }
    #pragma unroll
    for (int kk = 0; kk < 4; ++kk) {
        int i4 = t + kk * 256;
        int m = i4 >> 4, dq = i4 & 15;
        float4 v = *(const float4*)&Wk[(size_t)(mt * 64 + m) * DMODEL + h * 64 + dq * 4];
        Bt[m][dq * 4 + 0] = v.x; Bt[m][dq * 4 + 1] = v.y;
        Bt[m][dq * 4 + 2] = v.z; Bt[m][dq * 4 + 3] = v.w;
    }
    __syncthreads();

    const int c = t & 63, rg = t >> 6;
    float acc[8] = {0.f,0.f,0.f,0.f,0.f,0.f,0.f,0.f};
    #pragma unroll
    for (int dq = 0; dq < 16; ++dq) {
        float b0 = Bt[c][dq * 4 + 0], b1 = Bt[c][dq * 4 + 1];
        float b2 = Bt[c][dq * 4 + 2], b3 = Bt[c][dq * 4 + 3];
        #pragma unroll
        for (int i = 0; i < 8; ++i) {
            float4 a = *(const float4*)&Qt[rg * 8 + i][dq * 4];
            acc[i] += a.x * b0 + a.y * b1 + a.z * b2 + a.w * b3;
        }
    }
    #pragma unroll
    for (int i = 0; i < 8; ++i)
        u[(size_t)(rt * 32 + rg * 8 + i) * BIW + h * DMODEL + mt * 64 + c] = acc[i];

    if (mt == 0 && t < 32) {
        float s = 0.f;
        for (int d = 0; d < 64; ++d) s += bk[h * 64 + d] * Qt[t][d];
        cvec[(rt * 32 + t) * NHEADS + h] = s;
    }
}

// ---------------------------------------------------------------------------
// scores_k v3: u resident in registers, key streamed with PING-PONG register
// double-buffering (batch b+1 loads issue before batch b FMAs -> latency
// hidden under compute). grid (512 bi, 2 row-halves), 256 threads (4 waves).
// Wave wv owns heads wv*3..+3; per batch: 4 rows x 3 chunks = 12 float4 loads,
// 144 FMA, 30-shfl split-tree, 3 stores from lanes 0/16/32/48.
// launch_bounds(256,2): VGPR cap 256 -> no spill, no 64-cap clamp.
// ---------------------------------------------------------------------------
__global__ __launch_bounds__(256, 2) void scores_k(
    const float* __restrict__ key, const float* __restrict__ u,
    const float* __restrict__ cvec, const float* __restrict__ mask,
    float* __restrict__ sc_out)
{
    const int bi   = blockIdx.x;
    const int jh   = blockIdx.y;
    const int t    = threadIdx.x;
    const int lane = t & 63;
    const int wv   = t >> 6;              // wave 0..3
    const int h0   = wv * 3;
    const size_t kvb = (size_t)bi * 64 * DMODEL;
    const float* kbase = &key[kvb + lane * 4];

    // resident u fragments uf[i][cch]: u[bi, h0+i, cch*256 + lane*4 ..+4]
    float4 uf[3][3];
    #pragma unroll
    for (int i = 0; i < 3; ++i)
        #pragma unroll
        for (int cch = 0; cch < 3; ++cch)
            uf[i][cch] = *(const float4*)&u[(size_t)bi * BIW + (h0 + i) * DMODEL + cch * 256 + lane * 4];

    const float cv0 = cvec[bi * NHEADS + h0 + 0];
    const float cv1 = cvec[bi * NHEADS + h0 + 1];
    const float cv2 = cvec[bi * NHEADS + h0 + 2];

    float4 kA[12], kB[12];

    auto LOADK = [&](float4* kk, int b) {
        const float* kp = kbase + (size_t)(jh * 32 + b * 4) * DMODEL;
        #pragma unroll
        for (int r = 0; r < 4; ++r)
            #pragma unroll
            for (int cch = 0; cch < 3; ++cch)
                kk[r * 3 + cch] = *(const float4*)(kp + (size_t)r * DMODEL + cch * 256);
    };

    auto COMPUTE = [&](const float4* kk, int b) {
        const int j0 = jh * 32 + b * 4;
        float v[3][4];
        #pragma unroll
        for (int i = 0; i < 3; ++i)
            #pragma unroll
            for (int r = 0; r < 4; ++r) v[i][r] = 0.f;

        #pragma unroll
        for (int cch = 0; cch < 3; ++cch)
            #pragma unroll
            for (int i = 0; i < 3; ++i) {
                const float4 uu = uf[i][cch];
                #pragma unroll
                for (int r = 0; r < 4; ++r) {
                    const float4 kr = kk[r * 3 + cch];
                    v[i][r] += kr.x * uu.x + kr.y * uu.y + kr.z * uu.z + kr.w * uu.w;
                }
            }

        // reduce 12 values over 64 lanes
        float s[3][2];
        #pragma unroll
        for (int i = 0; i < 3; ++i)
            #pragma unroll
            for (int r = 0; r < 2; ++r) {
                float lo = v[i][r], hi = v[i][r + 2];
                float tl = __shfl_xor(lo, 32), th = __shfl_xor(hi, 32);
                s[i][r] = (lane < 32) ? lo + tl : hi + th;
            }
        float tt[3];
        #pragma unroll
        for (int i = 0; i < 3; ++i) {
            float lo = s[i][0], hi = s[i][1];
            float tl = __shfl_xor(lo, 16), th = __shfl_xor(hi, 16);
            tt[i] = ((lane & 16) == 0) ? lo + tl : hi + th;
        }
        #pragma unroll
        for (int o = 8; o >= 1; o >>= 1)
            #pragma unroll
            for (int i = 0; i < 3; ++i) tt[i] += __shfl_xor(tt[i], o);

        if ((lane & 15) == 0) {
            const int q = lane >> 4;          // quarter -> row j0+q
            const int j = j0 + q;
            const float mk = mask[bi * 64 + j];
            sc_out[(size_t)bi * 768 + (h0 + 0) * 64 + j] = (tt[0] + cv0) * mk;
            sc_out[(size_t)bi * 768 + (h0 + 1) * 64 + j] = (tt[1] + cv1) * mk;
            sc_out[(size_t)bi * 768 + (h0 + 2) * 64 + j] = (tt[2] + cv2) * mk;
        }
    };

    LOADK(kA, 0);
    #pragma unroll 1
    for (int b = 0; b < 8; b += 2) {
        LOADK(kB, b + 1);
        COMPUTE(kA, b);
        if (b + 2 < 8) LOADK(kA, b + 2);
        COMPUTE(kB, b + 1);
    }
}

// ---------------------------------------------------------------------------
// pv_k: grid (512 bi, 3 m-chunks), 256 threads, 3 KB LDS.
// Softmax per head (wave wv -> heads wv*3..+3), then w[h][m] = sum_j attn*value.
// j-loop unroll 4 -> 16 value loads in flight.
// ---------------------------------------------------------------------------
__global__ __launch_bounds__(256) void pv_k(
    const float* __restrict__ value, const float* __restrict__ sc,
    float* __restrict__ w)
{
    __shared__ float attn[NHEADS][64];    // 3 KB

    const int bi   = blockIdx.x;
    const int ms   = blockIdx.y;
    const int t    = threadIdx.x;
    const int lane = t & 63;
    const int wv   = t >> 6;              // wave 0..3
    const size_t kvb = (size_t)bi * 64 * DMODEL;

    // softmax: wave wv handles heads wv*3 .. wv*3+2 (scores already masked+biased)
    #pragma unroll
    for (int i = 0; i < 3; ++i) {
        const int h = wv * 3 + i;
        float s = sc[(size_t)bi * 768 + h * 64 + lane];
        float mx = s;
        #pragma unroll
        for (int o = 1; o < 64; o <<= 1) mx = fmaxf(mx, __shfl_xor(mx, o));
        float e = __expf(s - mx);
        float sm = e;
        #pragma unroll
        for (int o = 1; o < 64; o <<= 1) sm += __shfl_xor(sm, o);
        attn[h][lane] = e / sm;
    }
    __syncthreads();

    // PV: thread owns column m = ms*256 + t
    const int mo = ms * 256 + t;
    float acc[NHEADS];
    #pragma unroll
    for (int h = 0; h < NHEADS; ++h) acc[h] = 0.f;
    const float* vb = value + kvb + mo;

    #pragma unroll 4
    for (int j4 = 0; j4 < 64; j4 += 4) {
        float v0 = vb[(size_t)(j4 + 0) * DMODEL];
        float v1 = vb[(size_t)(j4 + 1) * DMODEL];
        float v2 = vb[(size_t)(j4 + 2) * DMODEL];
        float v3 = vb[(size_t)(j4 + 3) * DMODEL];
        #pragma unroll
        for (int h = 0; h < NHEADS; ++h) {
            float4 at = *(const float4*)&attn[h][j4];   // lane-uniform -> LDS broadcast
            acc[h] += at.x * v0 + at.y * v1 + at.z * v2 + at.w * v3;
        }
    }
    #pragma unroll
    for (int h = 0; h < NHEADS; ++h)
        w[(size_t)bi * BIW + h * DMODEL + mo] = acc[h];
}

// ---------------------------------------------------------------------------
extern "C" void kernel_launch(void* const* d_in, const int* in_sizes, int n_in,
                              void* d_out, int out_size, void* d_ws, size_t ws_size,
                              hipStream_t stream) {
    const float* key   = (const float*)d_in[0];
    const float* value = (const float*)d_in[1];
    const float* query = (const float*)d_in[2];
    const float* mask  = (const float*)d_in[3];
    const float* Wk    = (const float*)d_in[4];
    const float* bk    = (const float*)d_in[5];
    const float* Wv    = (const float*)d_in[6];
    const float* bv    = (const float*)d_in[7];
    const float* Wq    = (const float*)d_in[8];
    const float* bq    = (const float*)d_in[9];
    const float* Wo    = (const float*)d_in[10];
    const float* bo    = (const float*)d_in[11];
    float* out = (float*)d_out;

    float* wsf    = (float*)d_ws;
    float* qp_ctx = wsf;                                // 512*768 (Qp, later ctx)
    float* u_w    = wsf + (size_t)RTOT * DMODEL;        // 512*9216 (u, later w)
    float* cvec   = u_w + (size_t)RTOT * BIW;           // 512*12
    float* sc_ws  = cvec + (size_t)RTOT * NHEADS;       // 512*768 scores

    // 1. Qp = (query @ Wq + bq) / 8
    linear16<<<dim3(32, 24), 256, 0, stream>>>(query, DMODEL, 0, Wq, bq, qp_ctx, DMODEL, 0.125f);
    // 2. u[r,h,m], cvec[r,h]
    u_kernel<<<dim3(16, 12, 12), 256, 0, stream>>>(qp_ctx, Wk, bk, u_w, cvec);
    // 3a. masked scores
    scores_k<<<dim3(512, 2), 256, 0, stream>>>(key, u_w, cvec, mask, sc_ws);
    // 3b. softmax + PV (w overwrites u region; kernel boundary orders the reuse)
    pv_k<<<dim3(512, 3), 256, 0, stream>>>(value, sc_ws, u_w);
    // 4. ctx[r, h*64+cc] = w[r,h,:] @ Wv[:, h*64+cc] + bv
    linear16<<<dim3(32, 24), 256, 0, stream>>>(u_w, BIW, DMODEL, Wv, bv, qp_ctx, DMODEL, 1.0f);
    // 5. out = ctx @ Wo + bo
    linear16<<<dim3(32, 24), 256, 0, stream>>>(qp_ctx, DMODEL, 0, Wo, bo, out, DMODEL, 1.0f);
}

// Round 11
// 171.464 us; speedup vs baseline: 1.0020x; 1.0020x over previous
//
#include <hip/hip_runtime.h>

// Problem constants: B=8, L=64, D=768, H=12, d=64
#define DMODEL 768
#define NHEADS 12
#define RTOT   512           // B*L rows
#define BIW    9216          // NHEADS*DMODEL (per-(b,i) u/w row)

// ---------------------------------------------------------------------------
// 16x32-tile fp32 GEMM, register-double-buffered K chunks of 64.
// grid = (32, 24), 256 threads
// ---------------------------------------------------------------------------
__global__ __launch_bounds__(256) void linear16(
    const float* __restrict__ src, int ars, int scm,
    const float* __restrict__ W, const float* __restrict__ bias,
    float* __restrict__ dst, int drs, float scale)
{
    __shared__ float At[16][64];   // 4 KB
    __shared__ float Bt[64][32];   // 8 KB
    const int rt = blockIdx.x, ct = blockIdx.y, t = threadIdx.x;
    const int sk = ((ct * 32) >> 6) * scm;
    const int c  = t & 31;
    const int rg = t >> 5;             // 8 groups x 2 rows

    const int ar0 = t >> 4,          ak0 = t & 15;          // 1 float4 A
    const int bk0 = t >> 3,          bc0 = (t & 7) * 4;     // 2 float4 B
    const int bk1 = (t + 256) >> 3,  bc1 = ((t + 256) & 7) * 4;

    float4 va0, vb0, vb1;
    auto LD = [&](int kb) {
        va0 = *(const float4*)&src[(size_t)(rt * 16 + ar0) * ars + sk + kb * 64 + ak0 * 4];
        vb0 = *(const float4*)&W[(size_t)(kb * 64 + bk0) * DMODEL + ct * 32 + bc0];
        vb1 = *(const float4*)&W[(size_t)(kb * 64 + bk1) * DMODEL + ct * 32 + bc1];
    };

    LD(0);
    float acc[2] = {0.f, 0.f};

    for (int kb = 0; kb < 12; ++kb) {
        if (kb) __syncthreads();
        *(float4*)&At[ar0][ak0 * 4] = va0;
        *(float4*)&Bt[bk0][bc0] = vb0;
        *(float4*)&Bt[bk1][bc1] = vb1;
        __syncthreads();
        if (kb < 11) LD(kb + 1);
        #pragma unroll
        for (int kq = 0; kq < 16; ++kq) {
            float b0 = Bt[kq * 4 + 0][c], b1 = Bt[kq * 4 + 1][c];
            float b2 = Bt[kq * 4 + 2][c], b3 = Bt[kq * 4 + 3][c];
            #pragma unroll
            for (int i = 0; i < 2; ++i) {
                float4 a = *(const float4*)&At[rg * 2 + i][kq * 4];
                acc[i] += a.x * b0 + a.y * b1 + a.z * b2 + a.w * b3;
            }
        }
    }
    const float bb = bias[ct * 32 + c];
    #pragma unroll
    for (int i = 0; i < 2; ++i)
        dst[(size_t)(rt * 16 + rg * 2 + i) * drs + ct * 32 + c] = (acc[i] + bb) * scale;
}

// ---------------------------------------------------------------------------
// u[r, h, m] = sum_d Qp[r, h*64+d] * Wk[m, h*64+d];  cvec[r,h] = sum_d bk[h*64+d]*Qp[r,h*64+d]
// grid = (16, 12, 12), 256 threads
// ---------------------------------------------------------------------------
__global__ __launch_bounds__(256) void u_kernel(
    const float* __restrict__ qp, const float* __restrict__ Wk, const float* __restrict__ bk,
    float* __restrict__ u, float* __restrict__ cvec)
{
    __shared__ float Qt[32][64];    // 8 KB
    __shared__ float Bt[64][65];    // 16.25 KB (pad -> conflict-free b32 row reads)
    const int rt = blockIdx.x, mt = blockIdx.y, h = blockIdx.z, t = threadIdx.x;

    #pragma unroll
    for (int kk = 0; kk < 2; ++kk) {
        int i4 = t + kk * 256;
        int r = i4 >> 4, dq = i4 & 15;
        *(float4*)&Qt[r][dq * 4] =
            *(const float4*)&qp[(size_t)(rt * 32 + r) * DMODEL + h * 64 + dq * 4];
    }
    #pragma unroll
    for (int kk = 0; kk < 4; ++kk) {
        int i4 = t + kk * 256;
        int m = i4 >> 4, dq = i4 & 15;
        float4 v = *(const float4*)&Wk[(size_t)(mt * 64 + m) * DMODEL + h * 64 + dq * 4];
        Bt[m][dq * 4 + 0] = v.x; Bt[m][dq * 4 + 1] = v.y;
        Bt[m][dq * 4 + 2] = v.z; Bt[m][dq * 4 + 3] = v.w;
    }
    __syncthreads();

    const int c = t & 63, rg = t >> 6;
    float acc[8] = {0.f,0.f,0.f,0.f,0.f,0.f,0.f,0.f};
    #pragma unroll
    for (int dq = 0; dq < 16; ++dq) {
        float b0 = Bt[c][dq * 4 + 0], b1 = Bt[c][dq * 4 + 1];
        float b2 = Bt[c][dq * 4 + 2], b3 = Bt[c][dq * 4 + 3];
        #pragma unroll
        for (int i = 0; i < 8; ++i) {
            float4 a = *(const float4*)&Qt[rg * 8 + i][dq * 4];
            acc[i] += a.x * b0 + a.y * b1 + a.z * b2 + a.w * b3;
        }
    }
    #pragma unroll
    for (int i = 0; i < 8; ++i)
        u[(size_t)(rt * 32 + rg * 8 + i) * BIW + h * DMODEL + mt * 64 + c] = acc[i];

    if (mt == 0 && t < 32) {
        float s = 0.f;
        for (int d = 0; d < 64; ++d) s += bk[h * 64 + d] * Qt[t][d];
        cvec[(rt * 32 + t) * NHEADS + h] = s;
    }
}

// ---------------------------------------------------------------------------
// scores_k v4: u resident in registers, key streamed, ping-pong batches.
// grid (512 bi, 4 row-quarters) = 2048 blocks, 256 threads (4 waves).
// Block (bi,jq): 16 rows = 4 batches of 4. VGPR ~84, 0 LDS -> 4 blocks/CU
// = 16 waves/CU (50% occ), 8 blocks queued per CU.
// ---------------------------------------------------------------------------
__global__ __launch_bounds__(256, 2) void scores_k(
    const float* __restrict__ key, const float* __restrict__ u,
    const float* __restrict__ cvec, const float* __restrict__ mask,
    float* __restrict__ sc_out)
{
    const int bi   = blockIdx.x;
    const int jq   = blockIdx.y;          // row-quarter 0..3
    const int t    = threadIdx.x;
    const int lane = t & 63;
    const int wv   = t >> 6;              // wave 0..3
    const int h0   = wv * 3;
    const size_t kvb = (size_t)bi * 64 * DMODEL;
    const float* kbase = &key[kvb + (size_t)jq * 16 * DMODEL + lane * 4];

    // resident u fragments uf[i][cch]: u[bi, h0+i, cch*256 + lane*4 ..+4]
    float4 uf[3][3];
    #pragma unroll
    for (int i = 0; i < 3; ++i)
        #pragma unroll
        for (int cch = 0; cch < 3; ++cch)
            uf[i][cch] = *(const float4*)&u[(size_t)bi * BIW + (h0 + i) * DMODEL + cch * 256 + lane * 4];

    const float cv0 = cvec[bi * NHEADS + h0 + 0];
    const float cv1 = cvec[bi * NHEADS + h0 + 1];
    const float cv2 = cvec[bi * NHEADS + h0 + 2];

    float4 kA[12], kB[12];

    auto LOADK = [&](float4* kk, int b) {
        const float* kp = kbase + (size_t)(b * 4) * DMODEL;
        #pragma unroll
        for (int r = 0; r < 4; ++r)
            #pragma unroll
            for (int cch = 0; cch < 3; ++cch)
                kk[r * 3 + cch] = *(const float4*)(kp + (size_t)r * DMODEL + cch * 256);
    };

    auto COMPUTE = [&](const float4* kk, int b) {
        const int j0 = jq * 16 + b * 4;
        float v[3][4];
        #pragma unroll
        for (int i = 0; i < 3; ++i)
            #pragma unroll
            for (int r = 0; r < 4; ++r) v[i][r] = 0.f;

        #pragma unroll
        for (int cch = 0; cch < 3; ++cch)
            #pragma unroll
            for (int i = 0; i < 3; ++i) {
                const float4 uu = uf[i][cch];
                #pragma unroll
                for (int r = 0; r < 4; ++r) {
                    const float4 kr = kk[r * 3 + cch];
                    v[i][r] += kr.x * uu.x + kr.y * uu.y + kr.z * uu.z + kr.w * uu.w;
                }
            }

        // reduce 12 values over 64 lanes
        float s[3][2];
        #pragma unroll
        for (int i = 0; i < 3; ++i)
            #pragma unroll
            for (int r = 0; r < 2; ++r) {
                float lo = v[i][r], hi = v[i][r + 2];
                float tl = __shfl_xor(lo, 32), th = __shfl_xor(hi, 32);
                s[i][r] = (lane < 32) ? lo + tl : hi + th;
            }
        float tt[3];
        #pragma unroll
        for (int i = 0; i < 3; ++i) {
            float lo = s[i][0], hi = s[i][1];
            float tl = __shfl_xor(lo, 16), th = __shfl_xor(hi, 16);
            tt[i] = ((lane & 16) == 0) ? lo + tl : hi + th;
        }
        #pragma unroll
        for (int o = 8; o >= 1; o >>= 1)
            #pragma unroll
            for (int i = 0; i < 3; ++i) tt[i] += __shfl_xor(tt[i], o);

        if ((lane & 15) == 0) {
            const int q = lane >> 4;          // quarter -> row j0+q
            const int j = j0 + q;
            const float mk = mask[bi * 64 + j];
            sc_out[(size_t)bi * 768 + (h0 + 0) * 64 + j] = (tt[0] + cv0) * mk;
            sc_out[(size_t)bi * 768 + (h0 + 1) * 64 + j] = (tt[1] + cv1) * mk;
            sc_out[(size_t)bi * 768 + (h0 + 2) * 64 + j] = (tt[2] + cv2) * mk;
        }
    };

    LOADK(kA, 0);
    #pragma unroll 1
    for (int b = 0; b < 4; b += 2) {
        LOADK(kB, b + 1);
        COMPUTE(kA, b);
        if (b + 2 < 4) LOADK(kA, b + 2);
        COMPUTE(kB, b + 1);
    }
}

// ---------------------------------------------------------------------------
// pv_k: grid (512 bi, 3 m-chunks), 256 threads, 3 KB LDS.
// Softmax per head (wave wv -> heads wv*3..+3), then w[h][m] = sum_j attn*value.
// ---------------------------------------------------------------------------
__global__ __launch_bounds__(256) void pv_k(
    const float* __restrict__ value, const float* __restrict__ sc,
    float* __restrict__ w)
{
    __shared__ float attn[NHEADS][64];    // 3 KB

    const int bi   = blockIdx.x;
    const int ms   = blockIdx.y;
    const int t    = threadIdx.x;
    const int lane = t & 63;
    const int wv   = t >> 6;              // wave 0..3
    const size_t kvb = (size_t)bi * 64 * DMODEL;

    // softmax: wave wv handles heads wv*3 .. wv*3+2 (scores already masked+biased)
    #pragma unroll
    for (int i = 0; i < 3; ++i) {
        const int h = wv * 3 + i;
        float s = sc[(size_t)bi * 768 + h * 64 + lane];
        float mx = s;
        #pragma unroll
        for (int o = 1; o < 64; o <<= 1) mx = fmaxf(mx, __shfl_xor(mx, o));
        float e = __expf(s - mx);
        float sm = e;
        #pragma unroll
        for (int o = 1; o < 64; o <<= 1) sm += __shfl_xor(sm, o);
        attn[h][lane] = e / sm;
    }
    __syncthreads();

    // PV: thread owns column m = ms*256 + t
    const int mo = ms * 256 + t;
    float acc[NHEADS];
    #pragma unroll
    for (int h = 0; h < NHEADS; ++h) acc[h] = 0.f;
    const float* vb = value + kvb + mo;

    #pragma unroll 2
    for (int j4 = 0; j4 < 64; j4 += 4) {
        float v0 = vb[(size_t)(j4 + 0) * DMODEL];
        float v1 = vb[(size_t)(j4 + 1) * DMODEL];
        float v2 = vb[(size_t)(j4 + 2) * DMODEL];
        float v3 = vb[(size_t)(j4 + 3) * DMODEL];
        #pragma unroll
        for (int h = 0; h < NHEADS; ++h) {
            float4 at = *(const float4*)&attn[h][j4];   // lane-uniform -> LDS broadcast
            acc[h] += at.x * v0 + at.y * v1 + at.z * v2 + at.w * v3;
        }
    }
    #pragma unroll
    for (int h = 0; h < NHEADS; ++h)
        w[(size_t)bi * BIW + h * DMODEL + mo] = acc[h];
}

// ---------------------------------------------------------------------------
extern "C" void kernel_launch(void* const* d_in, const int* in_sizes, int n_in,
                              void* d_out, int out_size, void* d_ws, size_t ws_size,
                              hipStream_t stream) {
    const float* key   = (const float*)d_in[0];
    const float* value = (const float*)d_in[1];
    const float* query = (const float*)d_in[2];
    const float* mask  = (const float*)d_in[3];
    const float* Wk    = (const float*)d_in[4];
    const float* bk    = (const float*)d_in[5];
    const float* Wv    = (const float*)d_in[6];
    const float* bv    = (const float*)d_in[7];
    const float* Wq    = (const float*)d_in[8];
    const float* bq    = (const float*)d_in[9];
    const float* Wo    = (const float*)d_in[10];
    const float* bo    = (const float*)d_in[11];
    float* out = (float*)d_out;

    float* wsf    = (float*)d_ws;
    float* qp_ctx = wsf;                                // 512*768 (Qp, later ctx)
    float* u_w    = wsf + (size_t)RTOT * DMODEL;        // 512*9216 (u, later w)
    float* cvec   = u_w + (size_t)RTOT * BIW;           // 512*12
    float* sc_ws  = cvec + (size_t)RTOT * NHEADS;       // 512*768 scores

    // 1. Qp = (query @ Wq + bq) / 8
    linear16<<<dim3(32, 24), 256, 0, stream>>>(query, DMODEL, 0, Wq, bq, qp_ctx, DMODEL, 0.125f);
    // 2. u[r,h,m], cvec[r,h]
    u_kernel<<<dim3(16, 12, 12), 256, 0, stream>>>(qp_ctx, Wk, bk, u_w, cvec);
    // 3a. masked scores
    scores_k<<<dim3(512, 4), 256, 0, stream>>>(key, u_w, cvec, mask, sc_ws);
    // 3b. softmax + PV (w overwrites u region; kernel boundary orders the reuse)
    pv_k<<<dim3(512, 3), 256, 0, stream>>>(value, sc_ws, u_w);
    // 4. ctx[r, h*64+cc] = w[r,h,:] @ Wv[:, h*64+cc] + bv
    linear16<<<dim3(32, 24), 256, 0, stream>>>(u_w, BIW, DMODEL, Wv, bv, qp_ctx, DMODEL, 1.0f);
    // 5. out = ctx @ Wo + bo
    linear16<<<dim3(32, 24), 256, 0, stream>>>(qp_ctx, DMODEL, 0, Wo, bo, out, DMODEL, 1.0f);
}

// Round 12
// 162.537 us; speedup vs baseline: 1.0570x; 1.0549x over previous
//
#include <hip/hip_runtime.h>

// Problem constants: B=8, L=64, D=768, H=12, d=64
#define DMODEL 768
#define NHEADS 12
#define RTOT   512           // B*L rows
#define BIW    9216          // NHEADS*DMODEL (per-(b,i) u/w row)

// ---------------------------------------------------------------------------
// 16x32-tile fp32 GEMM, register-double-buffered K chunks of 64.
// grid = (32, 24), 256 threads
// ---------------------------------------------------------------------------
__global__ __launch_bounds__(256) void linear16(
    const float* __restrict__ src, int ars, int scm,
    const float* __restrict__ W, const float* __restrict__ bias,
    float* __restrict__ dst, int drs, float scale)
{
    __shared__ float At[16][64];   // 4 KB
    __shared__ float Bt[64][32];   // 8 KB
    const int rt = blockIdx.x, ct = blockIdx.y, t = threadIdx.x;
    const int sk = ((ct * 32) >> 6) * scm;
    const int c  = t & 31;
    const int rg = t >> 5;             // 8 groups x 2 rows

    const int ar0 = t >> 4,          ak0 = t & 15;          // 1 float4 A
    const int bk0 = t >> 3,          bc0 = (t & 7) * 4;     // 2 float4 B
    const int bk1 = (t + 256) >> 3,  bc1 = ((t + 256) & 7) * 4;

    float4 va0, vb0, vb1;
    auto LD = [&](int kb) {
        va0 = *(const float4*)&src[(size_t)(rt * 16 + ar0) * ars + sk + kb * 64 + ak0 * 4];
        vb0 = *(const float4*)&W[(size_t)(kb * 64 + bk0) * DMODEL + ct * 32 + bc0];
        vb1 = *(const float4*)&W[(size_t)(kb * 64 + bk1) * DMODEL + ct * 32 + bc1];
    };

    LD(0);
    float acc[2] = {0.f, 0.f};

    for (int kb = 0; kb < 12; ++kb) {
        if (kb) __syncthreads();
        *(float4*)&At[ar0][ak0 * 4] = va0;
        *(float4*)&Bt[bk0][bc0] = vb0;
        *(float4*)&Bt[bk1][bc1] = vb1;
        __syncthreads();
        if (kb < 11) LD(kb + 1);
        #pragma unroll
        for (int kq = 0; kq < 16; ++kq) {
            float b0 = Bt[kq * 4 + 0][c], b1 = Bt[kq * 4 + 1][c];
            float b2 = Bt[kq * 4 + 2][c], b3 = Bt[kq * 4 + 3][c];
            #pragma unroll
            for (int i = 0; i < 2; ++i) {
                float4 a = *(const float4*)&At[rg * 2 + i][kq * 4];
                acc[i] += a.x * b0 + a.y * b1 + a.z * b2 + a.w * b3;
            }
        }
    }
    const float bb = bias[ct * 32 + c];
    #pragma unroll
    for (int i = 0; i < 2; ++i)
        dst[(size_t)(rt * 16 + rg * 2 + i) * drs + ct * 32 + c] = (acc[i] + bb) * scale;
}

// ---------------------------------------------------------------------------
// u[r, h, m] = sum_d Qp[r, h*64+d] * Wk[m, h*64+d];  cvec[r,h] = sum_d bk[h*64+d]*Qp[r,h*64+d]
// grid = (16, 12, 12), 256 threads
// ---------------------------------------------------------------------------
__global__ __launch_bounds__(256) void u_kernel(
    const float* __restrict__ qp, const float* __restrict__ Wk, const float* __restrict__ bk,
    float* __restrict__ u, float* __restrict__ cvec)
{
    __shared__ float Qt[32][64];    // 8 KB
    __shared__ float Bt[64][65];    // 16.25 KB (pad -> conflict-free b32 row reads)
    const int rt = blockIdx.x, mt = blockIdx.y, h = blockIdx.z, t = threadIdx.x;

    #pragma unroll
    for (int kk = 0; kk < 2; ++kk) {
        int i4 = t + kk * 256;
        int r = i4 >> 4, dq = i4 & 15;
        *(float4*)&Qt[r][dq * 4] =
            *(const float4*)&qp[(size_t)(rt * 32 + r) * DMODEL + h * 64 + dq * 4];
    }
    #pragma unroll
    for (int kk = 0; kk < 4; ++kk) {
        int i4 = t + kk * 256;
        int m = i4 >> 4, dq = i4 & 15;
        float4 v = *(const float4*)&Wk[(size_t)(mt * 64 + m) * DMODEL + h * 64 + dq * 4];
        Bt[m][dq * 4 + 0] = v.x; Bt[m][dq * 4 + 1] = v.y;
        Bt[m][dq * 4 + 2] = v.z; Bt[m][dq * 4 + 3] = v.w;
    }
    __syncthreads();

    const int c = t & 63, rg = t >> 6;
    float acc[8] = {0.f,0.f,0.f,0.f,0.f,0.f,0.f,0.f};
    #pragma unroll
    for (int dq = 0; dq < 16; ++dq) {
        float b0 = Bt[c][dq * 4 + 0], b1 = Bt[c][dq * 4 + 1];
        float b2 = Bt[c][dq * 4 + 2], b3 = Bt[c][dq * 4 + 3];
        #pragma unroll
        for (int i = 0; i < 8; ++i) {
            float4 a = *(const float4*)&Qt[rg * 8 + i][dq * 4];
            acc[i] += a.x * b0 + a.y * b1 + a.z * b2 + a.w * b3;
        }
    }
    #pragma unroll
    for (int i = 0; i < 8; ++i)
        u[(size_t)(rt * 32 + rg * 8 + i) * BIW + h * DMODEL + mt * 64 + c] = acc[i];

    if (mt == 0 && t < 32) {
        float s = 0.f;
        for (int d = 0; d < 64; ++d) s += bk[h * 64 + d] * Qt[t][d];
        cvec[(rt * 32 + t) * NHEADS + h] = s;
    }
}

// ---------------------------------------------------------------------------
// scores_k: u resident in registers, key streamed, ping-pong batches.
// grid (512 bi, 2 row-halves), 256 threads (4 waves); u read once per block
// (2x unique total -- (512,4) doubled u traffic, reverted).
// ---------------------------------------------------------------------------
__global__ __launch_bounds__(256, 2) void scores_k(
    const float* __restrict__ key, const float* __restrict__ u,
    const float* __restrict__ cvec, const float* __restrict__ mask,
    float* __restrict__ sc_out)
{
    const int bi   = blockIdx.x;
    const int jh   = blockIdx.y;
    const int t    = threadIdx.x;
    const int lane = t & 63;
    const int wv   = t >> 6;              // wave 0..3
    const int h0   = wv * 3;
    const size_t kvb = (size_t)bi * 64 * DMODEL;
    const float* kbase = &key[kvb + (size_t)jh * 32 * DMODEL + lane * 4];

    // resident u fragments uf[i][cch]: u[bi, h0+i, cch*256 + lane*4 ..+4]
    float4 uf[3][3];
    #pragma unroll
    for (int i = 0; i < 3; ++i)
        #pragma unroll
        for (int cch = 0; cch < 3; ++cch)
            uf[i][cch] = *(const float4*)&u[(size_t)bi * BIW + (h0 + i) * DMODEL + cch * 256 + lane * 4];

    const float cv0 = cvec[bi * NHEADS + h0 + 0];
    const float cv1 = cvec[bi * NHEADS + h0 + 1];
    const float cv2 = cvec[bi * NHEADS + h0 + 2];

    float4 kA[12], kB[12];

    auto LOADK = [&](float4* kk, int b) {
        const float* kp = kbase + (size_t)(b * 4) * DMODEL;
        #pragma unroll
        for (int r = 0; r < 4; ++r)
            #pragma unroll
            for (int cch = 0; cch < 3; ++cch)
                kk[r * 3 + cch] = *(const float4*)(kp + (size_t)r * DMODEL + cch * 256);
    };

    auto COMPUTE = [&](const float4* kk, int b) {
        const int j0 = jh * 32 + b * 4;
        float v[3][4];
        #pragma unroll
        for (int i = 0; i < 3; ++i)
            #pragma unroll
            for (int r = 0; r < 4; ++r) v[i][r] = 0.f;

        #pragma unroll
        for (int cch = 0; cch < 3; ++cch)
            #pragma unroll
            for (int i = 0; i < 3; ++i) {
                const float4 uu = uf[i][cch];
                #pragma unroll
                for (int r = 0; r < 4; ++r) {
                    const float4 kr = kk[r * 3 + cch];
                    v[i][r] += kr.x * uu.x + kr.y * uu.y + kr.z * uu.z + kr.w * uu.w;
                }
            }

        // reduce 12 values over 64 lanes
        float s[3][2];
        #pragma unroll
        for (int i = 0; i < 3; ++i)
            #pragma unroll
            for (int r = 0; r < 2; ++r) {
                float lo = v[i][r], hi = v[i][r + 2];
                float tl = __shfl_xor(lo, 32), th = __shfl_xor(hi, 32);
                s[i][r] = (lane < 32) ? lo + tl : hi + th;
            }
        float tt[3];
        #pragma unroll
        for (int i = 0; i < 3; ++i) {
            float lo = s[i][0], hi = s[i][1];
            float tl = __shfl_xor(lo, 16), th = __shfl_xor(hi, 16);
            tt[i] = ((lane & 16) == 0) ? lo + tl : hi + th;
        }
        #pragma unroll
        for (int o = 8; o >= 1; o >>= 1)
            #pragma unroll
            for (int i = 0; i < 3; ++i) tt[i] += __shfl_xor(tt[i], o);

        if ((lane & 15) == 0) {
            const int q = lane >> 4;          // quarter -> row j0+q
            const int j = j0 + q;
            const float mk = mask[bi * 64 + j];
            sc_out[(size_t)bi * 768 + (h0 + 0) * 64 + j] = (tt[0] + cv0) * mk;
            sc_out[(size_t)bi * 768 + (h0 + 1) * 64 + j] = (tt[1] + cv1) * mk;
            sc_out[(size_t)bi * 768 + (h0 + 2) * 64 + j] = (tt[2] + cv2) * mk;
        }
    };

    LOADK(kA, 0);
    #pragma unroll 1
    for (int b = 0; b < 8; b += 2) {
        LOADK(kB, b + 1);
        COMPUTE(kA, b);
        if (b + 2 < 8) LOADK(kA, b + 2);
        COMPUTE(kB, b + 1);
    }
}

// ---------------------------------------------------------------------------
// pv_k v2: float4 value loads + wave-level j-split.
// grid (512 bi, 3 m-chunks of 256 floats), 256 threads (4 waves).
// Wave wv owns j in [wv*16, wv*16+16); lane owns float4 column -> every value
// load is a coalesced 1KB dwordx4. Cross-wave reduce via 24 KB LDS (2-stage),
// coalesced float4 stores.
// ---------------------------------------------------------------------------
__global__ __launch_bounds__(256, 4) void pv_k(
    const float* __restrict__ value, const float* __restrict__ sc,
    float* __restrict__ w)
{
    __shared__ float  attn[NHEADS][64];        // 3 KB
    __shared__ float4 part[2][NHEADS][64];     // 24 KB

    const int bi   = blockIdx.x;
    const int ms   = blockIdx.y;
    const int t    = threadIdx.x;
    const int lane = t & 63;
    const int wv   = t >> 6;              // wave 0..3
    const size_t kvb = (size_t)bi * 64 * DMODEL;

    // softmax: wave wv handles heads wv*3 .. wv*3+2 (scores already masked+biased)
    #pragma unroll
    for (int i = 0; i < 3; ++i) {
        const int h = wv * 3 + i;
        float s = sc[(size_t)bi * 768 + h * 64 + lane];
        float mx = s;
        #pragma unroll
        for (int o = 1; o < 64; o <<= 1) mx = fmaxf(mx, __shfl_xor(mx, o));
        float e = __expf(s - mx);
        float sm = e;
        #pragma unroll
        for (int o = 1; o < 64; o <<= 1) sm += __shfl_xor(sm, o);
        attn[h][lane] = e / sm;
    }
    __syncthreads();

    // PV partials: wave wv handles its 16 j-rows; lane owns float4 column
    float4 acc[NHEADS];
    #pragma unroll
    for (int h = 0; h < NHEADS; ++h) acc[h] = make_float4(0.f, 0.f, 0.f, 0.f);

    const float* vb = value + kvb + ms * 256 + lane * 4;
    const int jbase = wv * 16;
    #pragma unroll 4
    for (int jj = 0; jj < 16; ++jj) {
        float4 v4 = *(const float4*)(vb + (size_t)(jbase + jj) * DMODEL);
        #pragma unroll
        for (int h = 0; h < NHEADS; ++h) {
            const float a = attn[h][jbase + jj];     // wave-uniform -> LDS broadcast
            acc[h].x += a * v4.x; acc[h].y += a * v4.y;
            acc[h].z += a * v4.z; acc[h].w += a * v4.w;
        }
    }

    // 2-stage cross-wave reduce
    if (wv < 2) {
        #pragma unroll
        for (int h = 0; h < NHEADS; ++h) part[wv][h][lane] = acc[h];
    }
    __syncthreads();
    if (wv >= 2) {
        #pragma unroll
        for (int h = 0; h < NHEADS; ++h) {
            float4 p = part[wv - 2][h][lane];
            p.x += acc[h].x; p.y += acc[h].y; p.z += acc[h].z; p.w += acc[h].w;
            part[wv - 2][h][lane] = p;
        }
    }
    __syncthreads();

    // combine + coalesced float4 stores (3 outputs/thread)
    #pragma unroll
    for (int k = 0; k < 3; ++k) {
        const int p = t + k * 256;
        const int h = p >> 6, c = p & 63;
        float4 r0 = part[0][h][c], r1 = part[1][h][c];
        float4 r;
        r.x = r0.x + r1.x; r.y = r0.y + r1.y;
        r.z = r0.z + r1.z; r.w = r0.w + r1.w;
        *(float4*)&w[(size_t)bi * BIW + h * DMODEL + ms * 256 + c * 4] = r;
    }
}

// ---------------------------------------------------------------------------
extern "C" void kernel_launch(void* const* d_in, const int* in_sizes, int n_in,
                              void* d_out, int out_size, void* d_ws, size_t ws_size,
                              hipStream_t stream) {
    const float* key   = (const float*)d_in[0];
    const float* value = (const float*)d_in[1];
    const float* query = (const float*)d_in[2];
    const float* mask  = (const float*)d_in[3];
    const float* Wk    = (const float*)d_in[4];
    const float* bk    = (const float*)d_in[5];
    const float* Wv    = (const float*)d_in[6];
    const float* bv    = (const float*)d_in[7];
    const float* Wq    = (const float*)d_in[8];
    const float* bq    = (const float*)d_in[9];
    const float* Wo    = (const float*)d_in[10];
    const float* bo    = (const float*)d_in[11];
    float* out = (float*)d_out;

    float* wsf    = (float*)d_ws;
    float* qp_ctx = wsf;                                // 512*768 (Qp, later ctx)
    float* u_w    = wsf + (size_t)RTOT * DMODEL;        // 512*9216 (u, later w)
    float* cvec   = u_w + (size_t)RTOT * BIW;           // 512*12
    float* sc_ws  = cvec + (size_t)RTOT * NHEADS;       // 512*768 scores

    // 1. Qp = (query @ Wq + bq) / 8
    linear16<<<dim3(32, 24), 256, 0, stream>>>(query, DMODEL, 0, Wq, bq, qp_ctx, DMODEL, 0.125f);
    // 2. u[r,h,m], cvec[r,h]
    u_kernel<<<dim3(16, 12, 12), 256, 0, stream>>>(qp_ctx, Wk, bk, u_w, cvec);
    // 3a. masked scores
    scores_k<<<dim3(512, 2), 256, 0, stream>>>(key, u_w, cvec, mask, sc_ws);
    // 3b. softmax + PV (w overwrites u region; kernel boundary orders the reuse)
    pv_k<<<dim3(512, 3), 256, 0, stream>>>(value, sc_ws, u_w);
    // 4. ctx[r, h*64+cc] = w[r,h,:] @ Wv[:, h*64+cc] + bv
    linear16<<<dim3(32, 24), 256, 0, stream>>>(u_w, BIW, DMODEL, Wv, bv, qp_ctx, DMODEL, 1.0f);
    // 5. out = ctx @ Wo + bo
    linear16<<<dim3(32, 24), 256, 0, stream>>>(qp_ctx, DMODEL, 0, Wo, bo, out, DMODEL, 1.0f);
}

// Round 13
// 158.618 us; speedup vs baseline: 1.0831x; 1.0247x over previous
//
#include <hip/hip_runtime.h>

// Problem constants: B=8, L=64, D=768, H=12, d=64
#define DMODEL 768
#define NHEADS 12
#define RTOT   512           // B*L rows
#define BIW    9216          // NHEADS*DMODEL (per-(b,i) u/w row)

// ---------------------------------------------------------------------------
// 16x32-tile fp32 GEMM, register-double-buffered K chunks of 64.
// grid = (32, 24), 256 threads
// ---------------------------------------------------------------------------
__global__ __launch_bounds__(256) void linear16(
    const float* __restrict__ src, int ars, int scm,
    const float* __restrict__ W, const float* __restrict__ bias,
    float* __restrict__ dst, int drs, float scale)
{
    __shared__ float At[16][64];   // 4 KB
    __shared__ float Bt[64][32];   // 8 KB
    const int rt = blockIdx.x, ct = blockIdx.y, t = threadIdx.x;
    const int sk = ((ct * 32) >> 6) * scm;
    const int c  = t & 31;
    const int rg = t >> 5;             // 8 groups x 2 rows

    const int ar0 = t >> 4,          ak0 = t & 15;          // 1 float4 A
    const int bk0 = t >> 3,          bc0 = (t & 7) * 4;     // 2 float4 B
    const int bk1 = (t + 256) >> 3,  bc1 = ((t + 256) & 7) * 4;

    float4 va0, vb0, vb1;
    auto LD = [&](int kb) {
        va0 = *(const float4*)&src[(size_t)(rt * 16 + ar0) * ars + sk + kb * 64 + ak0 * 4];
        vb0 = *(const float4*)&W[(size_t)(kb * 64 + bk0) * DMODEL + ct * 32 + bc0];
        vb1 = *(const float4*)&W[(size_t)(kb * 64 + bk1) * DMODEL + ct * 32 + bc1];
    };

    LD(0);
    float acc[2] = {0.f, 0.f};

    for (int kb = 0; kb < 12; ++kb) {
        if (kb) __syncthreads();
        *(float4*)&At[ar0][ak0 * 4] = va0;
        *(float4*)&Bt[bk0][bc0] = vb0;
        *(float4*)&Bt[bk1][bc1] = vb1;
        __syncthreads();
        if (kb < 11) LD(kb + 1);
        #pragma unroll
        for (int kq = 0; kq < 16; ++kq) {
            float b0 = Bt[kq * 4 + 0][c], b1 = Bt[kq * 4 + 1][c];
            float b2 = Bt[kq * 4 + 2][c], b3 = Bt[kq * 4 + 3][c];
            #pragma unroll
            for (int i = 0; i < 2; ++i) {
                float4 a = *(const float4*)&At[rg * 2 + i][kq * 4];
                acc[i] += a.x * b0 + a.y * b1 + a.z * b2 + a.w * b3;
            }
        }
    }
    const float bb = bias[ct * 32 + c];
    #pragma unroll
    for (int i = 0; i < 2; ++i)
        dst[(size_t)(rt * 16 + rg * 2 + i) * drs + ct * 32 + c] = (acc[i] + bb) * scale;
}

// ---------------------------------------------------------------------------
// u[r, h, m] = sum_d Qp[r, h*64+d] * Wk[m, h*64+d];  cvec[r,h] = sum_d bk[h*64+d]*Qp[r,h*64+d]
// grid = (16, 12, 12), 256 threads
// ---------------------------------------------------------------------------
__global__ __launch_bounds__(256) void u_kernel(
    const float* __restrict__ qp, const float* __restrict__ Wk, const float* __restrict__ bk,
    float* __restrict__ u, float* __restrict__ cvec)
{
    __shared__ float Qt[32][64];    // 8 KB
    __shared__ float Bt[64][65];    // 16.25 KB (pad -> conflict-free b32 row reads)
    const int rt = blockIdx.x, mt = blockIdx.y, h = blockIdx.z, t = threadIdx.x;

    #pragma unroll
    for (int kk = 0; kk < 2; ++kk) {
        int i4 = t + kk * 256;
        int r = i4 >> 4, dq = i4 & 15;
        *(float4*)&Qt[r][dq * 4] =
            *(const float4*)&qp[(size_t)(rt * 32 + r) * DMODEL + h * 64 + dq * 4];
    }
    #pragma unroll
    for (int kk = 0; kk < 4; ++kk) {
        int i4 = t + kk * 256;
        int m = i4 >> 4, dq = i4 & 15;
        float4 v = *(const float4*)&Wk[(size_t)(mt * 64 + m) * DMODEL + h * 64 + dq * 4];
        Bt[m][dq * 4 + 0] = v.x; Bt[m][dq * 4 + 1] = v.y;
        Bt[m][dq * 4 + 2] = v.z; Bt[m][dq * 4 + 3] = v.w;
    }
    __syncthreads();

    const int c = t & 63, rg = t >> 6;
    float acc[8] = {0.f,0.f,0.f,0.f,0.f,0.f,0.f,0.f};
    #pragma unroll
    for (int dq = 0; dq < 16; ++dq) {
        float b0 = Bt[c][dq * 4 + 0], b1 = Bt[c][dq * 4 + 1];
        float b2 = Bt[c][dq * 4 + 2], b3 = Bt[c][dq * 4 + 3];
        #pragma unroll
        for (int i = 0; i < 8; ++i) {
            float4 a = *(const float4*)&Qt[rg * 8 + i][dq * 4];
            acc[i] += a.x * b0 + a.y * b1 + a.z * b2 + a.w * b3;
        }
    }
    #pragma unroll
    for (int i = 0; i < 8; ++i)
        u[(size_t)(rt * 32 + rg * 8 + i) * BIW + h * DMODEL + mt * 64 + c] = acc[i];

    if (mt == 0 && t < 32) {
        float s = 0.f;
        for (int d = 0; d < 64; ++d) s += bk[h * 64 + d] * Qt[t][d];
        cvec[(rt * 32 + t) * NHEADS + h] = s;
    }
}

// ---------------------------------------------------------------------------
// scores_k v5: one block per bi, 512 threads (8 waves).
// Wave wv: heads h0=(wv&3)*3..+3, j-half jh=wv>>2 (32 rows, 8 batches of 4).
// u[bi] read once per block (wave pairs dedupe in L1/L2) -> u HBM traffic
// halves vs grid(512,2). 16 waves/CU resident (VGPR 84, 0 LDS).
// ---------------------------------------------------------------------------
__global__ __launch_bounds__(512, 2) void scores_k(
    const float* __restrict__ key, const float* __restrict__ u,
    const float* __restrict__ cvec, const float* __restrict__ mask,
    float* __restrict__ sc_out)
{
    const int bi   = blockIdx.x;
    const int t    = threadIdx.x;
    const int lane = t & 63;
    const int wv   = t >> 6;              // wave 0..7
    const int h0   = (wv & 3) * 3;
    const int jh   = wv >> 2;             // j-half 0..1
    const size_t kvb = (size_t)bi * 64 * DMODEL;
    const float* kbase = &key[kvb + (size_t)jh * 32 * DMODEL + lane * 4];

    // resident u fragments uf[i][cch]: u[bi, h0+i, cch*256 + lane*4 ..+4]
    float4 uf[3][3];
    #pragma unroll
    for (int i = 0; i < 3; ++i)
        #pragma unroll
        for (int cch = 0; cch < 3; ++cch)
            uf[i][cch] = *(const float4*)&u[(size_t)bi * BIW + (h0 + i) * DMODEL + cch * 256 + lane * 4];

    const float cv0 = cvec[bi * NHEADS + h0 + 0];
    const float cv1 = cvec[bi * NHEADS + h0 + 1];
    const float cv2 = cvec[bi * NHEADS + h0 + 2];

    float4 kA[12], kB[12];

    auto LOADK = [&](float4* kk, int b) {
        const float* kp = kbase + (size_t)(b * 4) * DMODEL;
        #pragma unroll
        for (int r = 0; r < 4; ++r)
            #pragma unroll
            for (int cch = 0; cch < 3; ++cch)
                kk[r * 3 + cch] = *(const float4*)(kp + (size_t)r * DMODEL + cch * 256);
    };

    auto COMPUTE = [&](const float4* kk, int b) {
        const int j0 = jh * 32 + b * 4;
        float v[3][4];
        #pragma unroll
        for (int i = 0; i < 3; ++i)
            #pragma unroll
            for (int r = 0; r < 4; ++r) v[i][r] = 0.f;

        #pragma unroll
        for (int cch = 0; cch < 3; ++cch)
            #pragma unroll
            for (int i = 0; i < 3; ++i) {
                const float4 uu = uf[i][cch];
                #pragma unroll
                for (int r = 0; r < 4; ++r) {
                    const float4 kr = kk[r * 3 + cch];
                    v[i][r] += kr.x * uu.x + kr.y * uu.y + kr.z * uu.z + kr.w * uu.w;
                }
            }

        // reduce 12 values over 64 lanes
        float s[3][2];
        #pragma unroll
        for (int i = 0; i < 3; ++i)
            #pragma unroll
            for (int r = 0; r < 2; ++r) {
                float lo = v[i][r], hi = v[i][r + 2];
                float tl = __shfl_xor(lo, 32), th = __shfl_xor(hi, 32);
                s[i][r] = (lane < 32) ? lo + tl : hi + th;
            }
        float tt[3];
        #pragma unroll
        for (int i = 0; i < 3; ++i) {
            float lo = s[i][0], hi = s[i][1];
            float tl = __shfl_xor(lo, 16), th = __shfl_xor(hi, 16);
            tt[i] = ((lane & 16) == 0) ? lo + tl : hi + th;
        }
        #pragma unroll
        for (int o = 8; o >= 1; o >>= 1)
            #pragma unroll
            for (int i = 0; i < 3; ++i) tt[i] += __shfl_xor(tt[i], o);

        if ((lane & 15) == 0) {
            const int q = lane >> 4;          // quarter -> row j0+q
            const int j = j0 + q;
            const float mk = mask[bi * 64 + j];
            sc_out[(size_t)bi * 768 + (h0 + 0) * 64 + j] = (tt[0] + cv0) * mk;
            sc_out[(size_t)bi * 768 + (h0 + 1) * 64 + j] = (tt[1] + cv1) * mk;
            sc_out[(size_t)bi * 768 + (h0 + 2) * 64 + j] = (tt[2] + cv2) * mk;
        }
    };

    LOADK(kA, 0);
    #pragma unroll 1
    for (int b = 0; b < 8; b += 2) {
        LOADK(kB, b + 1);
        COMPUTE(kA, b);
        if (b + 2 < 8) LOADK(kA, b + 2);
        COMPUTE(kB, b + 1);
    }
}

// ---------------------------------------------------------------------------
// pv_k v2: float4 value loads + wave-level j-split.
// grid (512 bi, 3 m-chunks of 256 floats), 256 threads (4 waves).
// ---------------------------------------------------------------------------
__global__ __launch_bounds__(256, 4) void pv_k(
    const float* __restrict__ value, const float* __restrict__ sc,
    float* __restrict__ w)
{
    __shared__ float  attn[NHEADS][64];        // 3 KB
    __shared__ float4 part[2][NHEADS][64];     // 24 KB

    const int bi   = blockIdx.x;
    const int ms   = blockIdx.y;
    const int t    = threadIdx.x;
    const int lane = t & 63;
    const int wv   = t >> 6;              // wave 0..3
    const size_t kvb = (size_t)bi * 64 * DMODEL;

    // softmax: wave wv handles heads wv*3 .. wv*3+2 (scores already masked+biased)
    #pragma unroll
    for (int i = 0; i < 3; ++i) {
        const int h = wv * 3 + i;
        float s = sc[(size_t)bi * 768 + h * 64 + lane];
        float mx = s;
        #pragma unroll
        for (int o = 1; o < 64; o <<= 1) mx = fmaxf(mx, __shfl_xor(mx, o));
        float e = __expf(s - mx);
        float sm = e;
        #pragma unroll
        for (int o = 1; o < 64; o <<= 1) sm += __shfl_xor(sm, o);
        attn[h][lane] = e / sm;
    }
    __syncthreads();

    // PV partials: wave wv handles its 16 j-rows; lane owns float4 column
    float4 acc[NHEADS];
    #pragma unroll
    for (int h = 0; h < NHEADS; ++h) acc[h] = make_float4(0.f, 0.f, 0.f, 0.f);

    const float* vb = value + kvb + ms * 256 + lane * 4;
    const int jbase = wv * 16;
    #pragma unroll 4
    for (int jj = 0; jj < 16; ++jj) {
        float4 v4 = *(const float4*)(vb + (size_t)(jbase + jj) * DMODEL);
        #pragma unroll
        for (int h = 0; h < NHEADS; ++h) {
            const float a = attn[h][jbase + jj];     // wave-uniform -> LDS broadcast
            acc[h].x += a * v4.x; acc[h].y += a * v4.y;
            acc[h].z += a * v4.z; acc[h].w += a * v4.w;
        }
    }

    // 2-stage cross-wave reduce
    if (wv < 2) {
        #pragma unroll
        for (int h = 0; h < NHEADS; ++h) part[wv][h][lane] = acc[h];
    }
    __syncthreads();
    if (wv >= 2) {
        #pragma unroll
        for (int h = 0; h < NHEADS; ++h) {
            float4 p = part[wv - 2][h][lane];
            p.x += acc[h].x; p.y += acc[h].y; p.z += acc[h].z; p.w += acc[h].w;
            part[wv - 2][h][lane] = p;
        }
    }
    __syncthreads();

    // combine + coalesced float4 stores (3 outputs/thread)
    #pragma unroll
    for (int k = 0; k < 3; ++k) {
        const int p = t + k * 256;
        const int h = p >> 6, c = p & 63;
        float4 r0 = part[0][h][c], r1 = part[1][h][c];
        float4 r;
        r.x = r0.x + r1.x; r.y = r0.y + r1.y;
        r.z = r0.z + r1.z; r.w = r0.w + r1.w;
        *(float4*)&w[(size_t)bi * BIW + h * DMODEL + ms * 256 + c * 4] = r;
    }
}

// ---------------------------------------------------------------------------
extern "C" void kernel_launch(void* const* d_in, const int* in_sizes, int n_in,
                              void* d_out, int out_size, void* d_ws, size_t ws_size,
                              hipStream_t stream) {
    const float* key   = (const float*)d_in[0];
    const float* value = (const float*)d_in[1];
    const float* query = (const float*)d_in[2];
    const float* mask  = (const float*)d_in[3];
    const float* Wk    = (const float*)d_in[4];
    const float* bk    = (const float*)d_in[5];
    const float* Wv    = (const float*)d_in[6];
    const float* bv    = (const float*)d_in[7];
    const float* Wq    = (const float*)d_in[8];
    const float* bq    = (const float*)d_in[9];
    const float* Wo    = (const float*)d_in[10];
    const float* bo    = (const float*)d_in[11];
    float* out = (float*)d_out;

    float* wsf    = (float*)d_ws;
    float* qp_ctx = wsf;                                // 512*768 (Qp, later ctx)
    float* u_w    = wsf + (size_t)RTOT * DMODEL;        // 512*9216 (u, later w)
    float* cvec   = u_w + (size_t)RTOT * BIW;           // 512*12
    float* sc_ws  = cvec + (size_t)RTOT * NHEADS;       // 512*768 scores

    // 1. Qp = (query @ Wq + bq) / 8
    linear16<<<dim3(32, 24), 256, 0, stream>>>(query, DMODEL, 0, Wq, bq, qp_ctx, DMODEL, 0.125f);
    // 2. u[r,h,m], cvec[r,h]
    u_kernel<<<dim3(16, 12, 12), 256, 0, stream>>>(qp_ctx, Wk, bk, u_w, cvec);
    // 3a. masked scores
    scores_k<<<512, 512, 0, stream>>>(key, u_w, cvec, mask, sc_ws);
    // 3b. softmax + PV (w overwrites u region; kernel boundary orders the reuse)
    pv_k<<<dim3(512, 3), 256, 0, stream>>>(value, sc_ws, u_w);
    // 4. ctx[r, h*64+cc] = w[r,h,:] @ Wv[:, h*64+cc] + bv
    linear16<<<dim3(32, 24), 256, 0, stream>>>(u_w, BIW, DMODEL, Wv, bv, qp_ctx, DMODEL, 1.0f);
    // 5. out = ctx @ Wo + bo
    linear16<<<dim3(32, 24), 256, 0, stream>>>(qp_ctx, DMODEL, 0, Wo, bo, out, DMODEL, 1.0f);
}